// Round 14
// baseline (129.174 us; speedup 1.0000x reference)
//
#include <hip/hip_runtime.h>

// Problem constants: B=256, C=64, H=W=48, E=5, DIM=65

typedef _Float16 f16;
typedef f16 f16x8 __attribute__((ext_vector_type(8)));
typedef f16 f16x4 __attribute__((ext_vector_type(4)));
typedef f16 f16x2 __attribute__((ext_vector_type(2)));
typedef __fp16 h16x2 __attribute__((ext_vector_type(2)));
typedef float f32x4 __attribute__((ext_vector_type(4)));

constexpr size_t OFF_POOLED = 0;                       // 256*256 f32 (old path)
constexpr size_t OFF_KERN   = 65536;                   // 256*4096 f16 (swizzled [b][oc][ic^((oc&7)<<3)])
constexpr size_t OFF_W1     = 65536 + 1048576;         // 9*32*64 f16 swizzled [kk][oc][ic^((oc&7)<<3)]
constexpr size_t OFF_W2     = OFF_W1 + 32*64*12;       // 9*64*32 f16 linear [kk][oc][ic]
constexpr size_t OFF_W3     = OFF_W2 + 64*32*12;       // 9*128*64 f16 linear [kk][oc][ic]
constexpr size_t OFF_H1     = OFF_W3 + 128*64*12;      // 256*576*32 f16 channel-last [b][pos][ic]
constexpr size_t OFF_XH     = OFF_H1 + (size_t)256*576*32/2;   // 256*48*48*64 f16 pre-swizzled
constexpr size_t OFF_PP     = OFF_XH + (size_t)256*48*48*64/2; // 256*48*128 f32 pool partials
constexpr size_t WS_NEED    = OFF_PP + (size_t)256*48*128;     // f32 elements

__device__ __forceinline__ float sigmoidf_(float z) {
    return __builtin_amdgcn_rcpf(1.0f + __expf(-z));
}

__device__ __forceinline__ f16x2 pkrtz(float a, float b) {
    h16x2 r = __builtin_amdgcn_cvt_pkrtz(a, b);
    f16x2 o; o[0] = (f16)r[0]; o[1] = (f16)r[1];
    return o;
}

__device__ __forceinline__ f16x8 pk8(const float* c) {
    f16x2 p0 = pkrtz(c[0], c[1]);
    f16x2 p1 = pkrtz(c[2], c[3]);
    f16x2 p2 = pkrtz(c[4], c[5]);
    f16x2 p3 = pkrtz(c[6], c[7]);
    f16x8 hv = { p0[0], p0[1], p1[0], p1[1], p2[0], p2[1], p3[0], p3[1] };
    return hv;
}

// pack 8 floats and store swizzled into LDS tile (old-path staging)
__device__ __forceinline__ void store_slot8(f16* glds, int row, int sc, int icg, const float* c) {
    *(f16x8*)&glds[(row * 50 + sc) * 64 + ((icg ^ (sc & 7)) << 3)] = pk8(c);
}

// ======================= device-side wnorm helper =========================
__device__ __forceinline__ void wnorm_one(int bo, int lane,
    const float* v1, const float* g1, const float* v2, const float* g2,
    const float* v3, const float* g3, float* ws)
{
    const float* v; const float* g; int IC, oc; int which;
    if (bo < 32)       { v = v1; g = g1; oc = bo;      IC = 64; which = 1; }
    else if (bo < 96)  { v = v2; g = g2; oc = bo - 32; IC = 32; which = 2; }
    else               { v = v3; g = g3; oc = bo - 96; IC = 64; which = 3; }
    int n = IC * 9;
    const float* vo = v + (size_t)oc * n;
    float s = 0.0f;
    for (int i = lane; i < n; i += 64) { float xv = vo[i]; s += xv * xv; }
    #pragma unroll
    for (int off = 32; off; off >>= 1) s += __shfl_down(s, off);
    float tot = __shfl(s, 0);
    float sc = g[oc] / sqrtf(tot);
    if (which == 1) {
        f16* o1 = (f16*)(ws + OFF_W1);
        for (int i = lane; i < n; i += 64) {
            int ic = i / 9, kk = i - ic * 9;
            o1[kk * 2048 + oc * 64 + (ic ^ ((oc & 7) << 3))] = (f16)(vo[i] * sc);
        }
    } else if (which == 2) {
        f16* o2 = (f16*)(ws + OFF_W2);
        for (int i = lane; i < n; i += 64) {
            int ic = i / 9, kk = i - ic * 9;
            o2[(kk * 64 + oc) * 32 + ic] = (f16)(vo[i] * sc);
        }
    } else {
        f16* o3 = (f16*)(ws + OFF_W3);
        for (int i = lane; i < n; i += 64) {
            int ic = i / 9, kk = i - ic * 9;
            o3[(kk * 128 + oc) * 64 + ic] = (f16)(vo[i] * sc);
        }
    }
}

// ======================= NEW PATH kernels =================================
// K_PREP_X: blocks 0..12287 = (b,row): build xh (fp16, pre-swizzled) +
//           per-row pool partials pp[b][row][wq*64+ch] (deterministic).
//           blocks 12288..12511 : weight-norm (one oc each, wave 0).
__global__ void __launch_bounds__(128)
k_prep_x(const float* __restrict__ x,
         const float* __restrict__ v1, const float* __restrict__ g1,
         const float* __restrict__ v2, const float* __restrict__ g2,
         const float* __restrict__ v3, const float* __restrict__ g3,
         float* __restrict__ ws)
{
    const int blk = blockIdx.x;
    const int t = threadIdx.x;
    if (blk < 12288) {
        const int b = blk / 48, row = blk - 48 * b;
        __shared__ float part[12][64];
        f16* xh = (f16*)(ws + OFF_XH);
        if (t < 96) {
            const int icg = t & 7, colg = t >> 3;        // 8 icg x 12 colg
            const float4* xp = (const float4*)x + ((size_t)(b * 64 + icg * 8)) * 576 + row * 12 + colg;
            float4 va[8];
            #pragma unroll
            for (int i = 0; i < 8; i++) va[i] = xp[i * 576];
            float c0[8], c1[8], c2c[8], c3[8];
            #pragma unroll
            for (int i = 0; i < 8; i++) { c0[i] = va[i].x; c1[i] = va[i].y; c2c[i] = va[i].z; c3[i] = va[i].w; }
            size_t xb = ((size_t)b * 48 + row) * 48;
            int g0 = colg * 4;
            *(f16x8*)&xh[(xb + g0 + 0) * 64 + ((icg ^ ((g0 + 1) & 7)) << 3)] = pk8(c0);
            *(f16x8*)&xh[(xb + g0 + 1) * 64 + ((icg ^ ((g0 + 2) & 7)) << 3)] = pk8(c1);
            *(f16x8*)&xh[(xb + g0 + 2) * 64 + ((icg ^ ((g0 + 3) & 7)) << 3)] = pk8(c2c);
            *(f16x8*)&xh[(xb + g0 + 3) * 64 + ((icg ^ ((g0 + 4) & 7)) << 3)] = pk8(c3);
            #pragma unroll
            for (int i = 0; i < 8; i++)
                part[colg][icg * 8 + i] = va[i].x + va[i].y + va[i].z + va[i].w;
        }
        __syncthreads();
        {
            int ch = t & 63, wq = t >> 6;
            float s = 0.f;
            #pragma unroll
            for (int j = 0; j < 6; j++) s += part[wq * 6 + j][ch];
            ws[OFF_PP + ((size_t)b * 48 + row) * 128 + wq * 64 + ch] = s * (1.0f / 576.0f);
        }
    } else {
        if (t < 64) wnorm_one(blk - 12288, t, v1, g1, v2, g2, v3, g3, ws);
    }
}

// K_ROUTE_N: routing from pool partials + expert-mixed kern (swizzled fp16)
__global__ void k_route_n(const int* __restrict__ cluster,
                          const float* __restrict__ route_emb,
                          const float* __restrict__ route_W,
                          const float* __restrict__ route_b,
                          const float* __restrict__ expert_w,
                          float* __restrict__ ws)
{
    int b = blockIdx.x, t = threadIdx.x;
    __shared__ float feat[512];
    __shared__ float rwv[5];
    __shared__ float red[256];
    int cl = cluster[b];
    {   // pooled[b][c*4 + hb*2 + wb] = sum over 24 rows of pp (pre-scaled)
        int c = t >> 2, quad = t & 3;
        int hb_ = quad >> 1, wb_ = quad & 1;
        const float* pp = ws + OFF_PP + ((size_t)b * 48 + hb_ * 24) * 128 + wb_ * 64 + c;
        float s = 0.f;
        #pragma unroll 8
        for (int r = 0; r < 24; r++) s += pp[r * 128];
        feat[t] = s;
    }
    feat[256 + t] = route_emb[(size_t)cl * 256 + t];
    __syncthreads();
    float f0 = feat[t], f1 = feat[256 + t];
    for (int e = 0; e < 5; e++) {
        float pv = f0 * route_W[e * 512 + t] + f1 * route_W[e * 512 + 256 + t];
        red[t] = pv;
        __syncthreads();
        if (t < 128) red[t] += red[t + 128];
        __syncthreads();
        if (t < 64) {
            float s = red[t] + red[t + 64];
            #pragma unroll
            for (int off = 32; off; off >>= 1) s += __shfl_down(s, off);
            if (t == 0) rwv[e] = 1.0f / (1.0f + __expf(-(s + route_b[e])));
        }
        __syncthreads();
    }
    float r0 = rwv[0], r1 = rwv[1], r2 = rwv[2], r3 = rwv[3], r4 = rwv[4];
    f16* khg = (f16*)(ws + OFF_KERN);
    for (int j = t; j < 4096; j += 256) {
        int oc = j >> 6, ic = j & 63;
        float kv = r0 * expert_w[j] + r1 * expert_w[4096 + j] +
                   r2 * expert_w[2 * 4096 + j] + r3 * expert_w[3 * 4096 + j] +
                   r4 * expert_w[4 * 4096 + j];
        khg[(size_t)b * 4096 + oc * 64 + (ic ^ ((oc & 7) << 3))] = (f16)kv;
    }
}

// K_F1_N: x staged via global_load_lds from pre-swizzled xh (linear dest,
// pre-swizzled source — both-sides rule). Rest identical to r13 k_f1.
__global__ void __launch_bounds__(512, 4)
k_f1_n(const f16* __restrict__ xh, const f16* __restrict__ kernH,
       const float* __restrict__ cond_b, const f16* __restrict__ w1H,
       const float* __restrict__ cb1, const float* __restrict__ a1,
       f16* __restrict__ h1h)
{
    extern __shared__ char smem[];
    f16*  glds  = (f16*)smem;                  // 64000 B
    f16*  kh    = (f16*)(smem + 64000);        // 8192 B
    float* cbl  = (float*)(smem + 72192);      // 256 B
    f16*  hm    = (f16*)smem;                  // overlay: 13312 B (glds dead after P2)

    const int t = threadIdx.x;
    const int tile = blockIdx.x;            // 0..5
    const int b = blockIdx.y;
    const int r0 = tile * 8;
    const int w = t >> 6, l = t & 63;
    const int l15 = l & 15, agrp = l >> 4;

    // ---- P0: kern copy + cond_b + border zeros + x DMA (60 x 1KB segs) ----
    ((uint4*)kh)[t] = ((const uint4*)(kernH + (size_t)b * 4096))[t];
    if (t < 64) cbl[t] = cond_b[t];
    if (t < 160) {
        int row = t >> 4, rem = t & 15;
        int col = (rem >= 8) ? 49 : 0;
        int slot = rem & 7;
        uint4 z = {};
        *(uint4*)&glds[(row * 50 + col) * 64 + slot * 8] = z;
    }
    for (int e2 = w; e2 < 60; e2 += 8) {       // wave-uniform row/seg
        int row = e2 / 6, seg = e2 - 6 * row;
        int r_in = r0 - 1 + row;
        f16* dst = glds + (row * 50 + 1) * 64 + seg * 512;
        if (r_in >= 0 && r_in < 48) {
            const f16* src = xh + ((size_t)b * 48 + r_in) * 3072 + seg * 512 + l * 8;
            __builtin_amdgcn_global_load_lds((const uint32_t*)src, (uint32_t*)dst, 16, 0, 0);
        } else {
            uint4 z = {};
            *(uint4*)&dst[l * 8] = z;
        }
    }
    __syncthreads();

    // ---- P1: cc 1x1 conv via MFMA (A=kern, B=x) + gate in place ----
    {
        const int nt0 = (w < 6) ? 4 * w : 24 + 3 * (w - 6);
        const int NT  = (w < 6) ? 4 : 3;
        f32x4 acc[4][4] = {};
        int srA[4], scA[4];
        #pragma unroll
        for (int j = 0; j < 4; j++) {
            int ntc = nt0 + ((j < NT) ? j : 0);
            int p = ntc * 16 + l15;
            srA[j] = p / 48; scA[j] = p - 48 * srA[j] + 1;
        }
        #pragma unroll
        for (int ks = 0; ks < 2; ks++) {
            f16x8 kfr[4];
            #pragma unroll
            for (int mt = 0; mt < 4; mt++) {
                int oc = mt * 16 + l15;
                kfr[mt] = *(const f16x8*)&kh[oc * 64 + (((ks * 4 + agrp) ^ (oc & 7)) << 3)];
            }
            #pragma unroll
            for (int j = 0; j < 4; j++) {
                f16x8 bfr = *(const f16x8*)&glds[(srA[j] * 50 + scA[j]) * 64 +
                                                 (((ks * 4 + agrp) ^ (scA[j] & 7)) << 3)];
                #pragma unroll
                for (int mt = 0; mt < 4; mt++)
                    acc[mt][j] = __builtin_amdgcn_mfma_f32_16x16x32_f16(kfr[mt], bfr, acc[mt][j], 0, 0, 0);
            }
        }
        f32x4 cbv[4];
        #pragma unroll
        for (int mt = 0; mt < 4; mt++) cbv[mt] = *(const f32x4*)&cbl[mt * 16 + 4 * agrp];
        #pragma unroll
        for (int j = 0; j < 4; j++) {
            if (j < NT) {
                int base = (srA[j] * 50 + scA[j]) * 64;
                int sw8 = (scA[j] & 7) << 3;
                #pragma unroll
                for (int mt = 0; mt < 4; mt++) {
                    int oc0 = mt * 16 + 4 * agrp;
                    int addr = base + (oc0 ^ sw8);
                    f16x4 xv4 = *(const f16x4*)&glds[addr];
                    float s0 = sigmoidf_(acc[mt][j][0] + cbv[mt][0]);
                    float s1 = sigmoidf_(acc[mt][j][1] + cbv[mt][1]);
                    float s2 = sigmoidf_(acc[mt][j][2] + cbv[mt][2]);
                    float s3 = sigmoidf_(acc[mt][j][3] + cbv[mt][3]);
                    f16x2 slo = pkrtz(s0, s1);
                    f16x2 shi = pkrtz(s2, s3);
                    f16x2 xlo = { xv4[0], xv4[1] };
                    f16x2 xhi = { xv4[2], xv4[3] };
                    f16x2 glo = slo * xlo;
                    f16x2 ghi = shi * xhi;
                    f16x4 g4 = { glo[0], glo[1], ghi[0], ghi[1] };
                    *(f16x4*)&glds[addr] = g4;
                }
            }
        }
    }
    __syncthreads();

    // ---- P2: conv1 3x3 via MFMA (A=x pos, B=w1 oc from GLOBAL) ----
    f32x4 c2[3][2] = {};
    {
        const int q = w;
        #pragma unroll
        for (int kt = 0; kt < 18; kt++) {
            const int kk = kt >> 1, hh = kt & 1;
            const int dy = kk / 3, dx = kk - dy * 3;
            f16x8 bfr2[2];
            #pragma unroll
            for (int nt = 0; nt < 2; nt++) {
                int oc = nt * 16 + l15;
                int slot = (hh * 4 + agrp) ^ (oc & 7);
                bfr2[nt] = *(const f16x8*)&w1H[(kk * 32 + oc) * 64 + slot * 8];
            }
            #pragma unroll
            for (int mtl = 0; mtl < 3; mtl++) {
                int sc = mtl * 16 + l15 + dx;
                int slot = (hh * 4 + agrp) ^ (sc & 7);
                f16x8 af = *(const f16x8*)&glds[((q + dy) * 50 + sc) * 64 + slot * 8];
                c2[mtl][0] = __builtin_amdgcn_mfma_f32_16x16x32_f16(af, bfr2[0], c2[mtl][0], 0, 0, 0);
                c2[mtl][1] = __builtin_amdgcn_mfma_f32_16x16x32_f16(af, bfr2[1], c2[mtl][1], 0, 0, 0);
            }
        }
    }
    __syncthreads();

    // ---- P3: in-register horizontal maxpool + f16 dump hm[q][oc][26] ----
    {
        const int q = w;
        #pragma unroll
        for (int mtl = 0; mtl < 3; mtl++)
            #pragma unroll
            for (int nt = 0; nt < 2; nt++) {
                float h0 = fmaxf(c2[mtl][nt][0], c2[mtl][nt][1]);
                float h1 = fmaxf(c2[mtl][nt][2], c2[mtl][nt][3]);
                f16x2 hp = pkrtz(h0, h1);
                int oc = nt * 16 + l15;
                int pp = mtl * 8 + 2 * agrp;
                *(f16x2*)&hm[(q * 32 + oc) * 26 + pp] = hp;
            }
    }
    __syncthreads();

    // ---- P4: vertical maxpool + bias + prelu -> h1h DIRECT (coalesced) ----
    {
        const float av = a1[0];
        #pragma unroll
        for (int k = 0; k < 6; k++) {
            int e = t + 512 * k;
            int oc = e & 31, pos2 = e >> 5;
            int pr = pos2 / 24, pc = pos2 - 24 * pr;
            float v0 = (float)hm[((2 * pr) * 32 + oc) * 26 + pc];
            float v1 = (float)hm[((2 * pr + 1) * 32 + oc) * 26 + pc];
            float v = fmaxf(v0, v1) + cb1[oc];
            v = (v >= 0.0f) ? v : av * v;
            h1h[((size_t)b * 576 + tile * 96 + pos2) * 32 + oc] = (f16)v;
        }
    }
}

// ======================= OLD PATH kernels (r13-proven fallback) ===========
__global__ void __launch_bounds__(256)
k_prep_o(const float* __restrict__ x,
         const float* __restrict__ v1, const float* __restrict__ g1,
         const float* __restrict__ v2, const float* __restrict__ g2,
         const float* __restrict__ v3, const float* __restrict__ g3,
         float* __restrict__ ws)
{
    const int blk = blockIdx.x;
    const int lane = threadIdx.x & 63;
    const int w = threadIdx.x >> 6;
    if (blk < 4096) {
        const int slab = blk * 4 + w;
        const float4* p = (const float4*)(x + (size_t)slab * 2304);
        float a0 = 0.f, a1 = 0.f, a2 = 0.f, a3 = 0.f;
        #pragma unroll
        for (int j = 0; j < 9; j++) {
            int i = lane + 64 * j;
            int row = i / 12, cg = i - 12 * row;
            float4 v = p[i];
            float s = v.x + v.y + v.z + v.w;
            bool hq = (row >= 24), wq = (cg >= 6);
            a0 += (!hq && !wq) ? s : 0.f;
            a1 += (!hq &&  wq) ? s : 0.f;
            a2 += ( hq && !wq) ? s : 0.f;
            a3 += ( hq &&  wq) ? s : 0.f;
        }
        #pragma unroll
        for (int off = 32; off; off >>= 1) {
            a0 += __shfl_down(a0, off);
            a1 += __shfl_down(a1, off);
            a2 += __shfl_down(a2, off);
            a3 += __shfl_down(a3, off);
        }
        if (lane == 0) {
            int b = slab >> 6, c = slab & 63;
            float* d = ws + OFF_POOLED + (size_t)b * 256 + c * 4;
            d[0] = a0 * (1.0f / 576.0f);
            d[1] = a1 * (1.0f / 576.0f);
            d[2] = a2 * (1.0f / 576.0f);
            d[3] = a3 * (1.0f / 576.0f);
        }
    } else {
        wnorm_one((blk - 4096) * 4 + w, lane, v1, g1, v2, g2, v3, g3, ws);
    }
}

__global__ void k_route_o(const int* __restrict__ cluster,
                          const float* __restrict__ route_emb,
                          const float* __restrict__ route_W,
                          const float* __restrict__ route_b,
                          const float* __restrict__ expert_w,
                          float* __restrict__ ws)
{
    int b = blockIdx.x, t = threadIdx.x;
    __shared__ float feat[512];
    __shared__ float rwv[5];
    __shared__ float red[256];
    int cl = cluster[b];
    feat[t]       = ws[OFF_POOLED + (size_t)b * 256 + t];
    feat[256 + t] = route_emb[(size_t)cl * 256 + t];
    __syncthreads();
    float f0 = feat[t], f1 = feat[256 + t];
    for (int e = 0; e < 5; e++) {
        float pv = f0 * route_W[e * 512 + t] + f1 * route_W[e * 512 + 256 + t];
        red[t] = pv;
        __syncthreads();
        if (t < 128) red[t] += red[t + 128];
        __syncthreads();
        if (t < 64) {
            float s = red[t] + red[t + 64];
            #pragma unroll
            for (int off = 32; off; off >>= 1) s += __shfl_down(s, off);
            if (t == 0) rwv[e] = 1.0f / (1.0f + __expf(-(s + route_b[e])));
        }
        __syncthreads();
    }
    float r0 = rwv[0], r1 = rwv[1], r2 = rwv[2], r3 = rwv[3], r4 = rwv[4];
    f16* khg = (f16*)(ws + OFF_KERN);
    for (int j = t; j < 4096; j += 256) {
        int oc = j >> 6, ic = j & 63;
        float kv = r0 * expert_w[j] + r1 * expert_w[4096 + j] +
                   r2 * expert_w[2 * 4096 + j] + r3 * expert_w[3 * 4096 + j] +
                   r4 * expert_w[4 * 4096 + j];
        khg[(size_t)b * 4096 + oc * 64 + (ic ^ ((oc & 7) << 3))] = (f16)kv;
    }
}

__global__ void __launch_bounds__(512, 4)
k_f1_o(const float* __restrict__ x, const f16* __restrict__ kernH,
       const float* __restrict__ cond_b, const f16* __restrict__ w1H,
       const float* __restrict__ cb1, const float* __restrict__ a1,
       f16* __restrict__ h1h)
{
    extern __shared__ char smem[];
    f16*  glds  = (f16*)smem;
    f16*  kh    = (f16*)(smem + 64000);
    float* cbl  = (float*)(smem + 72192);
    f16*  hm    = (f16*)smem;

    const int t = threadIdx.x;
    const int tile = blockIdx.x;
    const int b = blockIdx.y;
    const int r0 = tile * 8;
    const int w = t >> 6, l = t & 63;
    const int l15 = l & 15, agrp = l >> 4;

    ((uint4*)kh)[t] = ((const uint4*)(kernH + (size_t)b * 4096))[t];
    if (t < 64) cbl[t] = cond_b[t];
    if (t < 160) {
        int row = t >> 4, rem = t & 15;
        int col = (rem >= 8) ? 49 : 0;
        int slot = rem & 7;
        uint4 z = {};
        *(uint4*)&glds[(row * 50 + col) * 64 + slot * 8] = z;
    }
    for (int e = t; e < 960; e += 512) {
        int row = e / 96;
        int rem = e - row * 96;
        int colg = rem >> 3;
        int icg = rem & 7;
        int r_in = r0 - 1 + row;
        float4 va[8];
        if (r_in >= 0 && r_in < 48) {
            const float4* xp = (const float4*)x + ((size_t)(b * 64 + icg * 8)) * 576 + r_in * 12 + colg;
            #pragma unroll
            for (int i = 0; i < 8; i++) va[i] = xp[i * 576];
        } else {
            #pragma unroll
            for (int i = 0; i < 8; i++) va[i] = (float4){0.f, 0.f, 0.f, 0.f};
        }
        float c0[8], c1[8], c2c[8], c3[8];
        #pragma unroll
        for (int i = 0; i < 8; i++) { c0[i] = va[i].x; c1[i] = va[i].y; c2c[i] = va[i].z; c3[i] = va[i].w; }
        int scb = colg * 4 + 1;
        store_slot8(glds, row, scb + 0, icg, c0);
        store_slot8(glds, row, scb + 1, icg, c1);
        store_slot8(glds, row, scb + 2, icg, c2c);
        store_slot8(glds, row, scb + 3, icg, c3);
    }
    __syncthreads();

    {
        const int nt0 = (w < 6) ? 4 * w : 24 + 3 * (w - 6);
        const int NT  = (w < 6) ? 4 : 3;
        f32x4 acc[4][4] = {};
        int srA[4], scA[4];
        #pragma unroll
        for (int j = 0; j < 4; j++) {
            int ntc = nt0 + ((j < NT) ? j : 0);
            int p = ntc * 16 + l15;
            srA[j] = p / 48; scA[j] = p - 48 * srA[j] + 1;
        }
        #pragma unroll
        for (int ks = 0; ks < 2; ks++) {
            f16x8 kfr[4];
            #pragma unroll
            for (int mt = 0; mt < 4; mt++) {
                int oc = mt * 16 + l15;
                kfr[mt] = *(const f16x8*)&kh[oc * 64 + (((ks * 4 + agrp) ^ (oc & 7)) << 3)];
            }
            #pragma unroll
            for (int j = 0; j < 4; j++) {
                f16x8 bfr = *(const f16x8*)&glds[(srA[j] * 50 + scA[j]) * 64 +
                                                 (((ks * 4 + agrp) ^ (scA[j] & 7)) << 3)];
                #pragma unroll
                for (int mt = 0; mt < 4; mt++)
                    acc[mt][j] = __builtin_amdgcn_mfma_f32_16x16x32_f16(kfr[mt], bfr, acc[mt][j], 0, 0, 0);
            }
        }
        f32x4 cbv[4];
        #pragma unroll
        for (int mt = 0; mt < 4; mt++) cbv[mt] = *(const f32x4*)&cbl[mt * 16 + 4 * agrp];
        #pragma unroll
        for (int j = 0; j < 4; j++) {
            if (j < NT) {
                int base = (srA[j] * 50 + scA[j]) * 64;
                int sw8 = (scA[j] & 7) << 3;
                #pragma unroll
                for (int mt = 0; mt < 4; mt++) {
                    int oc0 = mt * 16 + 4 * agrp;
                    int addr = base + (oc0 ^ sw8);
                    f16x4 xv4 = *(const f16x4*)&glds[addr];
                    float s0 = sigmoidf_(acc[mt][j][0] + cbv[mt][0]);
                    float s1 = sigmoidf_(acc[mt][j][1] + cbv[mt][1]);
                    float s2 = sigmoidf_(acc[mt][j][2] + cbv[mt][2]);
                    float s3 = sigmoidf_(acc[mt][j][3] + cbv[mt][3]);
                    f16x2 slo = pkrtz(s0, s1);
                    f16x2 shi = pkrtz(s2, s3);
                    f16x2 xlo = { xv4[0], xv4[1] };
                    f16x2 xhi = { xv4[2], xv4[3] };
                    f16x2 glo = slo * xlo;
                    f16x2 ghi = shi * xhi;
                    f16x4 g4 = { glo[0], glo[1], ghi[0], ghi[1] };
                    *(f16x4*)&glds[addr] = g4;
                }
            }
        }
    }
    __syncthreads();

    f32x4 c2[3][2] = {};
    {
        const int q = w;
        #pragma unroll
        for (int kt = 0; kt < 18; kt++) {
            const int kk = kt >> 1, hh = kt & 1;
            const int dy = kk / 3, dx = kk - dy * 3;
            f16x8 bfr2[2];
            #pragma unroll
            for (int nt = 0; nt < 2; nt++) {
                int oc = nt * 16 + l15;
                int slot = (hh * 4 + agrp) ^ (oc & 7);
                bfr2[nt] = *(const f16x8*)&w1H[(kk * 32 + oc) * 64 + slot * 8];
            }
            #pragma unroll
            for (int mtl = 0; mtl < 3; mtl++) {
                int sc = mtl * 16 + l15 + dx;
                int slot = (hh * 4 + agrp) ^ (sc & 7);
                f16x8 af = *(const f16x8*)&glds[((q + dy) * 50 + sc) * 64 + slot * 8];
                c2[mtl][0] = __builtin_amdgcn_mfma_f32_16x16x32_f16(af, bfr2[0], c2[mtl][0], 0, 0, 0);
                c2[mtl][1] = __builtin_amdgcn_mfma_f32_16x16x32_f16(af, bfr2[1], c2[mtl][1], 0, 0, 0);
            }
        }
    }
    __syncthreads();

    {
        const int q = w;
        #pragma unroll
        for (int mtl = 0; mtl < 3; mtl++)
            #pragma unroll
            for (int nt = 0; nt < 2; nt++) {
                float h0 = fmaxf(c2[mtl][nt][0], c2[mtl][nt][1]);
                float h1 = fmaxf(c2[mtl][nt][2], c2[mtl][nt][3]);
                f16x2 hp = pkrtz(h0, h1);
                int oc = nt * 16 + l15;
                int pp = mtl * 8 + 2 * agrp;
                *(f16x2*)&hm[(q * 32 + oc) * 26 + pp] = hp;
            }
    }
    __syncthreads();

    {
        const float av = a1[0];
        #pragma unroll
        for (int k = 0; k < 6; k++) {
            int e = t + 512 * k;
            int oc = e & 31, pos2 = e >> 5;
            int pr = pos2 / 24, pc = pos2 - 24 * pr;
            float v0 = (float)hm[((2 * pr) * 32 + oc) * 26 + pc];
            float v1 = (float)hm[((2 * pr + 1) * 32 + oc) * 26 + pc];
            float v = fmaxf(v0, v1) + cb1[oc];
            v = (v >= 0.0f) ? v : av * v;
            h1h[((size_t)b * 576 + tile * 96 + pos2) * 32 + oc] = (f16)v;
        }
    }
}

// ======================= F23 (shared, round-8-proven) =====================
__global__ void __launch_bounds__(1024, 1)
k_f23(const f16* __restrict__ h1h, const f16* __restrict__ w2h,
      const float* __restrict__ cb2, const float* __restrict__ a2,
      const f16* __restrict__ w3h, const float* __restrict__ cb3, const float* __restrict__ a3,
      const int* __restrict__ cluster, const float* __restrict__ emb2, const float* __restrict__ alpha,
      const float* __restrict__ mW1, const float* __restrict__ mb1, const float* __restrict__ a4,
      const float* __restrict__ mW2, const float* __restrict__ mb2, const float* __restrict__ a5,
      const float* __restrict__ mW3, const float* __restrict__ mb3,
      float* __restrict__ out)
{
    extern __shared__ char smem[];
    f16*  x2    = (f16*)smem;
    f16*  h2l   = (f16*)(smem + 82944);
    float* ps   = (float*)(smem + 111168);
    float* hb   = (float*)(smem + 113216);
    float* t1   = (float*)(smem + 113728);
    float* t2   = (float*)(smem + 113984);
    f16*  dump2 = (f16*)smem;
    f16*  dump3 = (f16*)smem;

    const int b = blockIdx.x, t = threadIdx.x;
    const int w = t >> 6, l = t & 63;
    const int l15 = l & 15, agrp = l >> 4;

    for (int e = t; e < 400; e += 1024) {
        int bp = e >> 2, slot = e & 3;
        int r, c;
        if (bp < 26)      { r = 0;  c = bp; }
        else if (bp < 52) { r = 25; c = bp - 26; }
        else if (bp < 76) { r = bp - 52 + 1; c = 0; }
        else              { r = bp - 76 + 1; c = 25; }
        uint4 z = {};
        *(uint4*)&x2[(r * 26 + c) * 40 + slot * 8] = z;
    }
    for (int e = t; e < 416; e += 1024) {
        int bp = e >> 3, slot = e & 7;
        int r, c;
        if (bp < 14)      { r = 0;  c = bp; }
        else if (bp < 28) { r = 13; c = bp - 14; }
        else if (bp < 40) { r = bp - 28 + 1; c = 0; }
        else              { r = bp - 40 + 1; c = 13; }
        uint4 z = {};
        *(uint4*)&h2l[(r * 14 + c) * 72 + slot * 8] = z;
    }
    {
        const uint4* src = (const uint4*)(h1h + (size_t)b * 18432);
        for (int e = t; e < 2304; e += 1024) {
            int pos = e >> 2, slot = e & 3;
            int r = pos / 24, c = pos - 24 * r;
            *(uint4*)&x2[((r + 1) * 26 + (c + 1)) * 40 + slot * 8] = src[e];
        }
    }
    __syncthreads();

    const int m = w & 3, ng = w >> 2;
    f32x4 acc[9];
    {
        f16x8 afr[9];
        #pragma unroll
        for (int kk = 0; kk < 9; kk++)
            afr[kk] = *(const f16x8*)&w2h[(kk * 64 + m * 16 + l15) * 32 + agrp * 8];
        #pragma unroll
        for (int i = 0; i < 9; i++) acc[i] = (f32x4){0.f, 0.f, 0.f, 0.f};
        constexpr int K2[9] = {0, 40, 80, 26 * 40, 27 * 40, 28 * 40, 52 * 40, 53 * 40, 54 * 40};
        #pragma unroll
        for (int i = 0; i < 9; i++) {
            int p = (ng * 9 + i) * 16 + l15;
            int r = p / 24, c = p - 24 * r;
            int base = (r * 26 + c) * 40 + agrp * 8;
            #pragma unroll
            for (int kk = 0; kk < 9; kk++) {
                f16x8 bfr = *(const f16x8*)&x2[base + K2[kk]];
                acc[i] = __builtin_amdgcn_mfma_f32_16x16x32_f16(afr[kk], bfr, acc[i], 0, 0, 0);
            }
        }
    }
    __syncthreads();

    #pragma unroll
    for (int i = 0; i < 9; i++) {
        int p = (ng * 9 + i) * 16 + l15;
        f16x2 d0 = pkrtz(acc[i][0], acc[i][1]);
        f16x2 d1 = pkrtz(acc[i][2], acc[i][3]);
        f16x4 hv = { d0[0], d0[1], d1[0], d1[1] };
        *(f16x4*)&dump2[p * 72 + m * 16 + 4 * agrp] = hv;
    }
    __syncthreads();

    {
        const float a2v = a2[0];
        for (int e = t; e < 9216; e += 1024) {
            int oc = e & 63, pos2 = e >> 6;
            int pr = pos2 / 12, pc = pos2 - 12 * pr;
            int p0 = (2 * pr) * 24 + 2 * pc;
            float mm = fmaxf(fmaxf((float)dump2[p0 * 72 + oc], (float)dump2[(p0 + 1) * 72 + oc]),
                             fmaxf((float)dump2[(p0 + 24) * 72 + oc], (float)dump2[(p0 + 25) * 72 + oc]));
            float v = mm + cb2[oc];
            v = (v >= 0.0f) ? v : a2v * v;
            h2l[((pr + 1) * 14 + (pc + 1)) * 72 + oc] = (f16)v;
        }
    }
    __syncthreads();

    const int m8 = w & 7, ng3 = w >> 3;
    const int nt0c3 = ng3 * 5;
    const int cnt3  = ng3 ? 4 : 5;
    f32x4 acc3[5];
    {
        int pb[5];
        #pragma unroll
        for (int i = 0; i < 5; i++) {
            int p = (nt0c3 + i) * 16 + l15;
            int r = p / 12, c = p - 12 * r;
            pb[i] = ((r + 1) * 14 + (c + 1)) * 72 + agrp * 8;
            acc3[i] = (f32x4){0.f, 0.f, 0.f, 0.f};
        }
        constexpr int K3[9] = {-15 * 72, -14 * 72, -13 * 72, -72, 0, 72, 13 * 72, 14 * 72, 15 * 72};
        #pragma unroll
        for (int kk = 0; kk < 9; kk++) {
            #pragma unroll
            for (int ks = 0; ks < 2; ks++) {
                f16x8 afr = *(const f16x8*)&w3h[(size_t)(kk * 128 + m8 * 16 + l15) * 64 + ks * 32 + agrp * 8];
                #pragma unroll
                for (int i = 0; i < 5; i++) {
                    if (i < cnt3) {
                        f16x8 bfr = *(const f16x8*)&h2l[pb[i] + ks * 32 + K3[kk]];
                        acc3[i] = __builtin_amdgcn_mfma_f32_16x16x32_f16(afr, bfr, acc3[i], 0, 0, 0);
                    }
                }
            }
        }
    }
    #pragma unroll
    for (int i = 0; i < 5; i++) {
        if (i < cnt3) {
            int p = (nt0c3 + i) * 16 + l15;
            f16x2 d0 = pkrtz(acc3[i][0], acc3[i][1]);
            f16x2 d1 = pkrtz(acc3[i][2], acc3[i][3]);
            f16x4 hv = { d0[0], d0[1], d1[0], d1[1] };
            *(f16x4*)&dump3[p * 136 + m8 * 16 + 4 * agrp] = hv;
        }
    }
    __syncthreads();

    if (t < 512) {
        int oc = t >> 2, q = t & 3;
        int qr = q >> 1, qc = q & 1;
        const float a3v = a3[0];
        float cbv = cb3[oc];
        float s = 0.f;
        #pragma unroll
        for (int i = 0; i < 3; i++)
            #pragma unroll
            for (int j = 0; j < 3; j++) {
                int pr = 3 * qr + i, pc = 3 * qc + j;
                int p0 = (2 * pr) * 12 + 2 * pc;
                float mm = fmaxf(fmaxf((float)dump3[p0 * 136 + oc], (float)dump3[(p0 + 1) * 136 + oc]),
                                 fmaxf((float)dump3[(p0 + 12) * 136 + oc], (float)dump3[(p0 + 13) * 136 + oc]));
                float v = mm + cbv;
                v = (v >= 0.0f) ? v : a3v * v;
                s += v;
            }
        ps[t] = s;
    }
    __syncthreads();
    if (t < 128) {
        int cl = cluster[b];
        hb[t] = (ps[4 * t] + ps[4 * t + 1] + ps[4 * t + 2] + ps[4 * t + 3]) * (1.0f / 36.0f)
              + emb2[(size_t)cl * 128 + t] * alpha[0];
    }
    __syncthreads();
    if (t < 64) {
        const float4* wr = (const float4*)(mW1 + t * 128);
        float s = mb1[t];
        #pragma unroll 8
        for (int j = 0; j < 32; j++) {
            float4 wv4 = wr[j];
            s += wv4.x * hb[4 * j] + wv4.y * hb[4 * j + 1] + wv4.z * hb[4 * j + 2] + wv4.w * hb[4 * j + 3];
        }
        float a4v = a4[0];
        t1[t] = (s >= 0.0f) ? s : a4v * s;
    }
    __syncthreads();
    if (t < 32) {
        const float4* wr = (const float4*)(mW2 + t * 64);
        float s = mb2[t];
        #pragma unroll
        for (int j = 0; j < 16; j++) {
            float4 wv4 = wr[j];
            s += wv4.x * t1[4 * j] + wv4.y * t1[4 * j + 1] + wv4.z * t1[4 * j + 2] + wv4.w * t1[4 * j + 3];
        }
        float a5v = a5[0];
        t2[t] = (s >= 0.0f) ? s : a5v * s;
    }
    __syncthreads();
    if (t < 65) {
        const float4* wr = (const float4*)(mW3 + t * 32);
        float s = mb3[t];
        #pragma unroll
        for (int j = 0; j < 8; j++) {
            float4 wv4 = wr[j];
            s += wv4.x * t2[4 * j] + wv4.y * t2[4 * j + 1] + wv4.z * t2[4 * j + 2] + wv4.w * t2[4 * j + 3];
        }
        out[(size_t)b * 65 + t] = s;
    }
}

// ---------------------------------------------------------------------------
extern "C" void kernel_launch(void* const* d_in, const int* in_sizes, int n_in,
                              void* d_out, int out_size, void* d_ws, size_t ws_size,
                              hipStream_t stream)
{
    const float* x         = (const float*)d_in[0];
    const int*   cluster   = (const int*)  d_in[1];
    const float* expert_w  = (const float*)d_in[2];
    const float* cond_b    = (const float*)d_in[3];
    const float* route_emb = (const float*)d_in[4];
    const float* route_W   = (const float*)d_in[5];
    const float* route_b   = (const float*)d_in[6];
    const float* v1  = (const float*)d_in[7];
    const float* g1  = (const float*)d_in[8];
    const float* cb1 = (const float*)d_in[9];
    const float* a1  = (const float*)d_in[10];
    const float* v2  = (const float*)d_in[11];
    const float* g2  = (const float*)d_in[12];
    const float* cb2 = (const float*)d_in[13];
    const float* a2  = (const float*)d_in[14];
    const float* v3  = (const float*)d_in[15];
    const float* g3  = (const float*)d_in[16];
    const float* cb3 = (const float*)d_in[17];
    const float* a3  = (const float*)d_in[18];
    const float* emb2  = (const float*)d_in[19];
    const float* alpha = (const float*)d_in[20];
    const float* mW1 = (const float*)d_in[21];
    const float* mb1 = (const float*)d_in[22];
    const float* a4  = (const float*)d_in[23];
    const float* mW2 = (const float*)d_in[24];
    const float* mb2 = (const float*)d_in[25];
    const float* a5  = (const float*)d_in[26];
    const float* mW3 = (const float*)d_in[27];
    const float* mb3 = (const float*)d_in[28];
    float* ws  = (float*)d_ws;
    float* out = (float*)d_out;

    hipFuncSetAttribute((const void*)k_f1_n, hipFuncAttributeMaxDynamicSharedMemorySize, 72448);
    hipFuncSetAttribute((const void*)k_f1_o, hipFuncAttributeMaxDynamicSharedMemorySize, 72448);
    hipFuncSetAttribute((const void*)k_f23,  hipFuncAttributeMaxDynamicSharedMemorySize, 114112);

    const bool big_ws = (ws_size >= WS_NEED * sizeof(float));   // deterministic

    if (big_ws) {
        k_prep_x<<<12512, 128, 0, stream>>>(x, v1, g1, v2, g2, v3, g3, ws);
        k_route_n<<<256, 256, 0, stream>>>(cluster, route_emb, route_W, route_b, expert_w, ws);
        k_f1_n<<<dim3(6, 256), 512, 72448, stream>>>((const f16*)(ws + OFF_XH),
                                                     (const f16*)(ws + OFF_KERN), cond_b,
                                                     (const f16*)(ws + OFF_W1), cb1, a1,
                                                     (f16*)(ws + OFF_H1));
    } else {
        k_prep_o<<<4152, 256, 0, stream>>>(x, v1, g1, v2, g2, v3, g3, ws);
        k_route_o<<<256, 256, 0, stream>>>(cluster, route_emb, route_W, route_b, expert_w, ws);
        k_f1_o<<<dim3(6, 256), 512, 72448, stream>>>(x, (const f16*)(ws + OFF_KERN), cond_b,
                                                     (const f16*)(ws + OFF_W1), cb1, a1,
                                                     (f16*)(ws + OFF_H1));
    }
    k_f23<<<256, 1024, 114112, stream>>>((const f16*)(ws + OFF_H1), (const f16*)(ws + OFF_W2),
                                         cb2, a2, (const f16*)(ws + OFF_W3), cb3, a3,
                                         cluster, emb2, alpha,
                                         mW1, mb1, a4, mW2, mb2, a5, mW3, mb3, out);
}

// Round 15
// 118.678 us; speedup vs baseline: 1.0884x; 1.0884x over previous
//
#include <hip/hip_runtime.h>

// Problem constants: B=256, C=64, H=W=48, E=5, DIM=65
// FINAL CONFIG (round-13-proven, 118.8 us): k_prep(256t) -> k_route -> k_f1
// (8-row tile, fp16 MFMA, XOR-swizzled LDS, direct pooled write) -> k_f23
// (1024t, fused conv2+conv3+MLP). 938 us (round-1 fp32 scalar) -> 118.8 us.

typedef _Float16 f16;
typedef f16 f16x8 __attribute__((ext_vector_type(8)));
typedef f16 f16x4 __attribute__((ext_vector_type(4)));
typedef f16 f16x2 __attribute__((ext_vector_type(2)));
typedef __fp16 h16x2 __attribute__((ext_vector_type(2)));
typedef float f32x4 __attribute__((ext_vector_type(4)));

constexpr size_t OFF_POOLED = 0;                       // 256*256 f32
constexpr size_t OFF_KERN   = 65536;                   // 256*4096 f16 (swizzled [b][oc][ic^((oc&7)<<3)])
constexpr size_t OFF_W1     = 65536 + 1048576;         // 9*32*64 f16 swizzled [kk][oc][ic^((oc&7)<<3)]
constexpr size_t OFF_W2     = OFF_W1 + 32*64*12;       // 9*64*32 f16 linear [kk][oc][ic]
constexpr size_t OFF_W3     = OFF_W2 + 64*32*12;       // 9*128*64 f16 linear [kk][oc][ic]
constexpr size_t OFF_H1     = OFF_W3 + 128*64*12;      // 256*576*32 f16 channel-last [b][pos][ic]

__device__ __forceinline__ float sigmoidf_(float z) {
    return __builtin_amdgcn_rcpf(1.0f + __expf(-z));
}

__device__ __forceinline__ f16x2 pkrtz(float a, float b) {
    h16x2 r = __builtin_amdgcn_cvt_pkrtz(a, b);
    f16x2 o; o[0] = (f16)r[0]; o[1] = (f16)r[1];
    return o;
}

__device__ __forceinline__ void store_slot8(f16* glds, int row, int sc, int icg, const float* c) {
    f16x2 p0 = pkrtz(c[0], c[1]);
    f16x2 p1 = pkrtz(c[2], c[3]);
    f16x2 p2 = pkrtz(c[4], c[5]);
    f16x2 p3 = pkrtz(c[6], c[7]);
    f16x8 hv = { p0[0], p0[1], p1[0], p1[1], p2[0], p2[1], p3[0], p3[1] };
    *(f16x8*)&glds[(row * 50 + sc) * 64 + ((icg ^ (sc & 7)) << 3)] = hv;
}

// ---------------------------------------------------------------------------
// K_PREP (256 threads, wave-per-unit):
//   blocks 0..4095    : pool — 4 (b,c) slabs per block
//   blocks 4096..4151 : weight-norm — 4 oc per block
// ---------------------------------------------------------------------------
__global__ void __launch_bounds__(256)
k_prep(const float* __restrict__ x,
       const float* __restrict__ v1, const float* __restrict__ g1,
       const float* __restrict__ v2, const float* __restrict__ g2,
       const float* __restrict__ v3, const float* __restrict__ g3,
       float* __restrict__ ws)
{
    const int blk = blockIdx.x;
    const int lane = threadIdx.x & 63;
    const int w = threadIdx.x >> 6;
    if (blk < 4096) {
        const int slab = blk * 4 + w;             // < 16384
        const float4* p = (const float4*)(x + (size_t)slab * 2304);
        float a0 = 0.f, a1 = 0.f, a2 = 0.f, a3 = 0.f;
        #pragma unroll
        for (int j = 0; j < 9; j++) {
            int i = lane + 64 * j;
            int row = i / 12, cg = i - 12 * row;
            float4 v = p[i];
            float s = v.x + v.y + v.z + v.w;
            bool hq = (row >= 24), wq = (cg >= 6);
            a0 += (!hq && !wq) ? s : 0.f;
            a1 += (!hq &&  wq) ? s : 0.f;
            a2 += ( hq && !wq) ? s : 0.f;
            a3 += ( hq &&  wq) ? s : 0.f;
        }
        #pragma unroll
        for (int off = 32; off; off >>= 1) {
            a0 += __shfl_down(a0, off);
            a1 += __shfl_down(a1, off);
            a2 += __shfl_down(a2, off);
            a3 += __shfl_down(a3, off);
        }
        if (lane == 0) {
            int b = slab >> 6, c = slab & 63;
            float* d = ws + OFF_POOLED + (size_t)b * 256 + c * 4;
            d[0] = a0 * (1.0f / 576.0f);
            d[1] = a1 * (1.0f / 576.0f);
            d[2] = a2 * (1.0f / 576.0f);
            d[3] = a3 * (1.0f / 576.0f);
        }
    } else {
        int bo = (blk - 4096) * 4 + w;            // < 224
        const float* v; const float* g; int IC, oc; int which;
        if (bo < 32)       { v = v1; g = g1; oc = bo;      IC = 64; which = 1; }
        else if (bo < 96)  { v = v2; g = g2; oc = bo - 32; IC = 32; which = 2; }
        else               { v = v3; g = g3; oc = bo - 96; IC = 64; which = 3; }
        int n = IC * 9;
        const float* vo = v + (size_t)oc * n;
        float s = 0.0f;
        for (int i = lane; i < n; i += 64) { float xv = vo[i]; s += xv * xv; }
        #pragma unroll
        for (int off = 32; off; off >>= 1) s += __shfl_down(s, off);
        float tot = __shfl(s, 0);
        float sc = g[oc] / sqrtf(tot);
        if (which == 1) {
            f16* o1 = (f16*)(ws + OFF_W1);
            for (int i = lane; i < n; i += 64) {
                int ic = i / 9, kk = i - ic * 9;
                o1[kk * 2048 + oc * 64 + (ic ^ ((oc & 7) << 3))] = (f16)(vo[i] * sc);
            }
        } else if (which == 2) {
            f16* o2 = (f16*)(ws + OFF_W2);
            for (int i = lane; i < n; i += 64) {
                int ic = i / 9, kk = i - ic * 9;
                o2[(kk * 64 + oc) * 32 + ic] = (f16)(vo[i] * sc);
            }
        } else {
            f16* o3 = (f16*)(ws + OFF_W3);
            for (int i = lane; i < n; i += 64) {
                int ic = i / 9, kk = i - ic * 9;
                o3[(kk * 128 + oc) * 64 + ic] = (f16)(vo[i] * sc);
            }
        }
    }
}

// ---------------------------------------------------------------------------
// K2: routing + expert-mixed 1x1 kern -> fp16 swizzled [b][oc][ic^((oc&7)<<3)]
// ---------------------------------------------------------------------------
__global__ void k_route(const int* __restrict__ cluster,
                        const float* __restrict__ route_emb,
                        const float* __restrict__ route_W,
                        const float* __restrict__ route_b,
                        const float* __restrict__ expert_w,
                        float* __restrict__ ws)
{
    int b = blockIdx.x, t = threadIdx.x;
    __shared__ float feat[512];
    __shared__ float rwv[5];
    __shared__ float red[256];
    int cl = cluster[b];
    feat[t]       = ws[OFF_POOLED + (size_t)b * 256 + t];
    feat[256 + t] = route_emb[(size_t)cl * 256 + t];
    __syncthreads();
    float f0 = feat[t], f1 = feat[256 + t];
    for (int e = 0; e < 5; e++) {
        float pv = f0 * route_W[e * 512 + t] + f1 * route_W[e * 512 + 256 + t];
        red[t] = pv;
        __syncthreads();
        if (t < 128) red[t] += red[t + 128];
        __syncthreads();
        if (t < 64) {
            float s = red[t] + red[t + 64];
            #pragma unroll
            for (int off = 32; off; off >>= 1) s += __shfl_down(s, off);
            if (t == 0) rwv[e] = 1.0f / (1.0f + __expf(-(s + route_b[e])));
        }
        __syncthreads();
    }
    float r0 = rwv[0], r1 = rwv[1], r2 = rwv[2], r3 = rwv[3], r4 = rwv[4];
    f16* khg = (f16*)(ws + OFF_KERN);
    for (int j = t; j < 4096; j += 256) {
        int oc = j >> 6, ic = j & 63;
        float kv = r0 * expert_w[j] + r1 * expert_w[4096 + j] +
                   r2 * expert_w[2 * 4096 + j] + r3 * expert_w[3 * 4096 + j] +
                   r4 * expert_w[4 * 4096 + j];
        khg[(size_t)b * 4096 + oc * 64 + (ic ^ ((oc & 7) << 3))] = (f16)kv;
    }
}

// ---------------------------------------------------------------------------
// F1 (MFMA): cc(1x1, A=kern M=oc, B=x N=pos) + gate + conv1 + prelu + pool
// -> h1h fp16 [b][576 pos][32 oc]
// 8-row tile, 6 tiles/sample, LDS 72448 B, direct P4 write.
// ---------------------------------------------------------------------------
__global__ void __launch_bounds__(512, 4)
k_f1(const float* __restrict__ x, const f16* __restrict__ kernH,
     const float* __restrict__ cond_b, const f16* __restrict__ w1H,
     const float* __restrict__ cb1, const float* __restrict__ a1,
     f16* __restrict__ h1h)
{
    extern __shared__ char smem[];
    f16*  glds  = (f16*)smem;                  // 64000 B
    f16*  kh    = (f16*)(smem + 64000);        // 8192 B
    float* cbl  = (float*)(smem + 72192);      // 256 B
    f16*  hm    = (f16*)smem;                  // overlay: 13312 B (glds dead after P2)

    const int t = threadIdx.x;
    const int tile = blockIdx.x;            // 0..5
    const int b = blockIdx.y;
    const int r0 = tile * 8;
    const int w = t >> 6, l = t & 63;
    const int l15 = l & 15, agrp = l >> 4;

    // ---- P0: stage kern + cond_b, zero border cols, stage x (8x4 reg transpose) ----
    ((uint4*)kh)[t] = ((const uint4*)(kernH + (size_t)b * 4096))[t];
    if (t < 64) cbl[t] = cond_b[t];
    if (t < 160) {
        int row = t >> 4, rem = t & 15;
        int col = (rem >= 8) ? 49 : 0;
        int slot = rem & 7;
        uint4 z = {};
        *(uint4*)&glds[(row * 50 + col) * 64 + slot * 8] = z;
    }
    for (int e = t; e < 960; e += 512) {
        int row = e / 96;
        int rem = e - row * 96;
        int colg = rem >> 3;
        int icg = rem & 7;
        int r_in = r0 - 1 + row;
        float4 va[8];
        if (r_in >= 0 && r_in < 48) {
            const float4* xp = (const float4*)x + ((size_t)(b * 64 + icg * 8)) * 576 + r_in * 12 + colg;
            #pragma unroll
            for (int i = 0; i < 8; i++) va[i] = xp[i * 576];
        } else {
            #pragma unroll
            for (int i = 0; i < 8; i++) va[i] = (float4){0.f, 0.f, 0.f, 0.f};
        }
        float c0[8], c1[8], c2c[8], c3[8];
        #pragma unroll
        for (int i = 0; i < 8; i++) { c0[i] = va[i].x; c1[i] = va[i].y; c2c[i] = va[i].z; c3[i] = va[i].w; }
        int scb = colg * 4 + 1;
        store_slot8(glds, row, scb + 0, icg, c0);
        store_slot8(glds, row, scb + 1, icg, c1);
        store_slot8(glds, row, scb + 2, icg, c2c);
        store_slot8(glds, row, scb + 3, icg, c3);
    }
    __syncthreads();

    // ---- P1: cc 1x1 conv via MFMA (A=kern, B=x) + gate in place (b64 RMW) ----
    {
        const int nt0 = (w < 6) ? 4 * w : 24 + 3 * (w - 6);
        const int NT  = (w < 6) ? 4 : 3;
        f32x4 acc[4][4] = {};
        int srA[4], scA[4];
        #pragma unroll
        for (int j = 0; j < 4; j++) {
            int ntc = nt0 + ((j < NT) ? j : 0);
            int p = ntc * 16 + l15;
            srA[j] = p / 48; scA[j] = p - 48 * srA[j] + 1;
        }
        #pragma unroll
        for (int ks = 0; ks < 2; ks++) {
            f16x8 kfr[4];
            #pragma unroll
            for (int mt = 0; mt < 4; mt++) {
                int oc = mt * 16 + l15;
                kfr[mt] = *(const f16x8*)&kh[oc * 64 + (((ks * 4 + agrp) ^ (oc & 7)) << 3)];
            }
            #pragma unroll
            for (int j = 0; j < 4; j++) {
                f16x8 bfr = *(const f16x8*)&glds[(srA[j] * 50 + scA[j]) * 64 +
                                                 (((ks * 4 + agrp) ^ (scA[j] & 7)) << 3)];
                #pragma unroll
                for (int mt = 0; mt < 4; mt++)
                    acc[mt][j] = __builtin_amdgcn_mfma_f32_16x16x32_f16(kfr[mt], bfr, acc[mt][j], 0, 0, 0);
            }
        }
        f32x4 cbv[4];
        #pragma unroll
        for (int mt = 0; mt < 4; mt++) cbv[mt] = *(const f32x4*)&cbl[mt * 16 + 4 * agrp];
        #pragma unroll
        for (int j = 0; j < 4; j++) {
            if (j < NT) {
                int base = (srA[j] * 50 + scA[j]) * 64;
                int sw8 = (scA[j] & 7) << 3;
                #pragma unroll
                for (int mt = 0; mt < 4; mt++) {
                    int oc0 = mt * 16 + 4 * agrp;
                    int addr = base + (oc0 ^ sw8);
                    f16x4 xv4 = *(const f16x4*)&glds[addr];
                    float s0 = sigmoidf_(acc[mt][j][0] + cbv[mt][0]);
                    float s1 = sigmoidf_(acc[mt][j][1] + cbv[mt][1]);
                    float s2 = sigmoidf_(acc[mt][j][2] + cbv[mt][2]);
                    float s3 = sigmoidf_(acc[mt][j][3] + cbv[mt][3]);
                    f16x2 slo = pkrtz(s0, s1);
                    f16x2 shi = pkrtz(s2, s3);
                    f16x2 xlo = { xv4[0], xv4[1] };
                    f16x2 xhi = { xv4[2], xv4[3] };
                    f16x2 glo = slo * xlo;
                    f16x2 ghi = shi * xhi;
                    f16x4 g4 = { glo[0], glo[1], ghi[0], ghi[1] };
                    *(f16x4*)&glds[addr] = g4;
                }
            }
        }
    }
    __syncthreads();

    // ---- P2: conv1 3x3 via MFMA (A=x pos, B=w1 oc from GLOBAL) ----
    f32x4 c2[3][2] = {};
    {
        const int q = w;
        #pragma unroll
        for (int kt = 0; kt < 18; kt++) {
            const int kk = kt >> 1, hh = kt & 1;
            const int dy = kk / 3, dx = kk - dy * 3;
            f16x8 bfr2[2];
            #pragma unroll
            for (int nt = 0; nt < 2; nt++) {
                int oc = nt * 16 + l15;
                int slot = (hh * 4 + agrp) ^ (oc & 7);
                bfr2[nt] = *(const f16x8*)&w1H[(kk * 32 + oc) * 64 + slot * 8];
            }
            #pragma unroll
            for (int mtl = 0; mtl < 3; mtl++) {
                int sc = mtl * 16 + l15 + dx;
                int slot = (hh * 4 + agrp) ^ (sc & 7);
                f16x8 af = *(const f16x8*)&glds[((q + dy) * 50 + sc) * 64 + slot * 8];
                c2[mtl][0] = __builtin_amdgcn_mfma_f32_16x16x32_f16(af, bfr2[0], c2[mtl][0], 0, 0, 0);
                c2[mtl][1] = __builtin_amdgcn_mfma_f32_16x16x32_f16(af, bfr2[1], c2[mtl][1], 0, 0, 0);
            }
        }
    }
    __syncthreads();   // glds reads done; hm overlays

    // ---- P3: in-register horizontal maxpool + f16 dump hm[q][oc][26] ----
    {
        const int q = w;
        #pragma unroll
        for (int mtl = 0; mtl < 3; mtl++)
            #pragma unroll
            for (int nt = 0; nt < 2; nt++) {
                float h0 = fmaxf(c2[mtl][nt][0], c2[mtl][nt][1]);
                float h1 = fmaxf(c2[mtl][nt][2], c2[mtl][nt][3]);
                f16x2 hp = pkrtz(h0, h1);
                int oc = nt * 16 + l15;
                int pp = mtl * 8 + 2 * agrp;
                *(f16x2*)&hm[(q * 32 + oc) * 26 + pp] = hp;
            }
    }
    __syncthreads();

    // ---- P4: vertical maxpool + bias + prelu -> h1h DIRECT (coalesced) ----
    {
        const float av = a1[0];
        #pragma unroll
        for (int k = 0; k < 6; k++) {
            int e = t + 512 * k;                 // 3072 = 96 pos2 x 32 oc
            int oc = e & 31, pos2 = e >> 5;
            int pr = pos2 / 24, pc = pos2 - 24 * pr;
            float v0 = (float)hm[((2 * pr) * 32 + oc) * 26 + pc];
            float v1 = (float)hm[((2 * pr + 1) * 32 + oc) * 26 + pc];
            float v = fmaxf(v0, v1) + cb1[oc];
            v = (v >= 0.0f) ? v : av * v;
            h1h[((size_t)b * 576 + tile * 96 + pos2) * 32 + oc] = (f16)v;
        }
    }
}

// ---------------------------------------------------------------------------
// F23 (MFMA): conv2+pool + conv3+pool + mean + emb + MLP, one block per sample
// 1024 threads / 16 waves.
// ---------------------------------------------------------------------------
__global__ void __launch_bounds__(1024, 1)
k_f23(const f16* __restrict__ h1h, const f16* __restrict__ w2h,
      const float* __restrict__ cb2, const float* __restrict__ a2,
      const f16* __restrict__ w3h, const float* __restrict__ cb3, const float* __restrict__ a3,
      const int* __restrict__ cluster, const float* __restrict__ emb2, const float* __restrict__ alpha,
      const float* __restrict__ mW1, const float* __restrict__ mb1, const float* __restrict__ a4,
      const float* __restrict__ mW2, const float* __restrict__ mb2, const float* __restrict__ a5,
      const float* __restrict__ mW3, const float* __restrict__ mb3,
      float* __restrict__ out)
{
    extern __shared__ char smem[];
    f16*  x2    = (f16*)smem;
    f16*  h2l   = (f16*)(smem + 82944);
    float* ps   = (float*)(smem + 111168);
    float* hb   = (float*)(smem + 113216);
    float* t1   = (float*)(smem + 113728);
    float* t2   = (float*)(smem + 113984);
    f16*  dump2 = (f16*)smem;
    f16*  dump3 = (f16*)smem;

    const int b = blockIdx.x, t = threadIdx.x;
    const int w = t >> 6, l = t & 63;
    const int l15 = l & 15, agrp = l >> 4;

    // ---- P0: zero borders + stage x2 ----
    for (int e = t; e < 400; e += 1024) {
        int bp = e >> 2, slot = e & 3;
        int r, c;
        if (bp < 26)      { r = 0;  c = bp; }
        else if (bp < 52) { r = 25; c = bp - 26; }
        else if (bp < 76) { r = bp - 52 + 1; c = 0; }
        else              { r = bp - 76 + 1; c = 25; }
        uint4 z = {};
        *(uint4*)&x2[(r * 26 + c) * 40 + slot * 8] = z;
    }
    for (int e = t; e < 416; e += 1024) {
        int bp = e >> 3, slot = e & 7;
        int r, c;
        if (bp < 14)      { r = 0;  c = bp; }
        else if (bp < 28) { r = 13; c = bp - 14; }
        else if (bp < 40) { r = bp - 28 + 1; c = 0; }
        else              { r = bp - 40 + 1; c = 13; }
        uint4 z = {};
        *(uint4*)&h2l[(r * 14 + c) * 72 + slot * 8] = z;
    }
    {
        const uint4* src = (const uint4*)(h1h + (size_t)b * 18432);
        for (int e = t; e < 2304; e += 1024) {
            int pos = e >> 2, slot = e & 3;
            int r = pos / 24, c = pos - 24 * r;
            *(uint4*)&x2[((r + 1) * 26 + (c + 1)) * 40 + slot * 8] = src[e];
        }
    }
    __syncthreads();

    // ---- P1: conv2 MFMA (m = w&3 oc-tile, ng = w>>2: 4 groups x 9 N-tiles = 36) ----
    const int m = w & 3, ng = w >> 2;
    f32x4 acc[9];
    {
        f16x8 afr[9];
        #pragma unroll
        for (int kk = 0; kk < 9; kk++)
            afr[kk] = *(const f16x8*)&w2h[(kk * 64 + m * 16 + l15) * 32 + agrp * 8];
        #pragma unroll
        for (int i = 0; i < 9; i++) acc[i] = (f32x4){0.f, 0.f, 0.f, 0.f};
        constexpr int K2[9] = {0, 40, 80, 26 * 40, 27 * 40, 28 * 40, 52 * 40, 53 * 40, 54 * 40};
        #pragma unroll
        for (int i = 0; i < 9; i++) {
            int p = (ng * 9 + i) * 16 + l15;
            int r = p / 24, c = p - 24 * r;
            int base = (r * 26 + c) * 40 + agrp * 8;
            #pragma unroll
            for (int kk = 0; kk < 9; kk++) {
                f16x8 bfr = *(const f16x8*)&x2[base + K2[kk]];
                acc[i] = __builtin_amdgcn_mfma_f32_16x16x32_f16(afr[kk], bfr, acc[i], 0, 0, 0);
            }
        }
    }
    __syncthreads();

    // ---- P2: dump2 [576][72] fp16 ----
    #pragma unroll
    for (int i = 0; i < 9; i++) {
        int p = (ng * 9 + i) * 16 + l15;
        f16x2 d0 = pkrtz(acc[i][0], acc[i][1]);
        f16x2 d1 = pkrtz(acc[i][2], acc[i][3]);
        f16x4 hv = { d0[0], d0[1], d1[0], d1[1] };
        *(f16x4*)&dump2[p * 72 + m * 16 + 4 * agrp] = hv;
    }
    __syncthreads();

    // ---- P3: pool conv2 + bias + prelu -> h2l [14][14][72] padded ----
    {
        const float a2v = a2[0];
        for (int e = t; e < 9216; e += 1024) {
            int oc = e & 63, pos2 = e >> 6;
            int pr = pos2 / 12, pc = pos2 - 12 * pr;
            int p0 = (2 * pr) * 24 + 2 * pc;
            float mm = fmaxf(fmaxf((float)dump2[p0 * 72 + oc], (float)dump2[(p0 + 1) * 72 + oc]),
                             fmaxf((float)dump2[(p0 + 24) * 72 + oc], (float)dump2[(p0 + 25) * 72 + oc]));
            float v = mm + cb2[oc];
            v = (v >= 0.0f) ? v : a2v * v;
            h2l[((pr + 1) * 14 + (pc + 1)) * 72 + oc] = (f16)v;
        }
    }
    __syncthreads();

    // ---- P4: conv3 MFMA (m8 = w&7 oc-tile, ng3 = w>>3: groups {5,4} = 9 N-tiles) ----
    const int m8 = w & 7, ng3 = w >> 3;
    const int nt0c3 = ng3 * 5;
    const int cnt3  = ng3 ? 4 : 5;
    f32x4 acc3[5];
    {
        int pb[5];
        #pragma unroll
        for (int i = 0; i < 5; i++) {
            int p = (nt0c3 + i) * 16 + l15;
            int r = p / 12, c = p - 12 * r;
            pb[i] = ((r + 1) * 14 + (c + 1)) * 72 + agrp * 8;
            acc3[i] = (f32x4){0.f, 0.f, 0.f, 0.f};
        }
        constexpr int K3[9] = {-15 * 72, -14 * 72, -13 * 72, -72, 0, 72, 13 * 72, 14 * 72, 15 * 72};
        #pragma unroll
        for (int kk = 0; kk < 9; kk++) {
            #pragma unroll
            for (int ks = 0; ks < 2; ks++) {
                f16x8 afr = *(const f16x8*)&w3h[(size_t)(kk * 128 + m8 * 16 + l15) * 64 + ks * 32 + agrp * 8];
                #pragma unroll
                for (int i = 0; i < 5; i++) {
                    if (i < cnt3) {
                        f16x8 bfr = *(const f16x8*)&h2l[pb[i] + ks * 32 + K3[kk]];
                        acc3[i] = __builtin_amdgcn_mfma_f32_16x16x32_f16(afr, bfr, acc3[i], 0, 0, 0);
                    }
                }
            }
        }
    }
    // ---- P5: dump3 [144][136] fp16 ----
    #pragma unroll
    for (int i = 0; i < 5; i++) {
        if (i < cnt3) {
            int p = (nt0c3 + i) * 16 + l15;
            f16x2 d0 = pkrtz(acc3[i][0], acc3[i][1]);
            f16x2 d1 = pkrtz(acc3[i][2], acc3[i][3]);
            f16x4 hv = { d0[0], d0[1], d1[0], d1[1] };
            *(f16x4*)&dump3[p * 136 + m8 * 16 + 4 * agrp] = hv;
        }
    }
    __syncthreads();

    // ---- P6: pool conv3 + bias + prelu + 9-element partial mean ----
    if (t < 512) {
        int oc = t >> 2, q = t & 3;
        int qr = q >> 1, qc = q & 1;
        const float a3v = a3[0];
        float cbv = cb3[oc];
        float s = 0.f;
        #pragma unroll
        for (int i = 0; i < 3; i++)
            #pragma unroll
            for (int j = 0; j < 3; j++) {
                int pr = 3 * qr + i, pc = 3 * qc + j;
                int p0 = (2 * pr) * 12 + 2 * pc;
                float mm = fmaxf(fmaxf((float)dump3[p0 * 136 + oc], (float)dump3[(p0 + 1) * 136 + oc]),
                                 fmaxf((float)dump3[(p0 + 12) * 136 + oc], (float)dump3[(p0 + 13) * 136 + oc]));
                float v = mm + cbv;
                v = (v >= 0.0f) ? v : a3v * v;
                s += v;
            }
        ps[t] = s;
    }
    __syncthreads();
    if (t < 128) {
        int cl = cluster[b];
        hb[t] = (ps[4 * t] + ps[4 * t + 1] + ps[4 * t + 2] + ps[4 * t + 3]) * (1.0f / 36.0f)
              + emb2[(size_t)cl * 128 + t] * alpha[0];
    }
    __syncthreads();
    if (t < 64) {
        const float4* wr = (const float4*)(mW1 + t * 128);
        float s = mb1[t];
        #pragma unroll 8
        for (int j = 0; j < 32; j++) {
            float4 wv4 = wr[j];
            s += wv4.x * hb[4 * j] + wv4.y * hb[4 * j + 1] + wv4.z * hb[4 * j + 2] + wv4.w * hb[4 * j + 3];
        }
        float a4v = a4[0];
        t1[t] = (s >= 0.0f) ? s : a4v * s;
    }
    __syncthreads();
    if (t < 32) {
        const float4* wr = (const float4*)(mW2 + t * 64);
        float s = mb2[t];
        #pragma unroll
        for (int j = 0; j < 16; j++) {
            float4 wv4 = wr[j];
            s += wv4.x * t1[4 * j] + wv4.y * t1[4 * j + 1] + wv4.z * t1[4 * j + 2] + wv4.w * t1[4 * j + 3];
        }
        float a5v = a5[0];
        t2[t] = (s >= 0.0f) ? s : a5v * s;
    }
    __syncthreads();
    if (t < 65) {
        const float4* wr = (const float4*)(mW3 + t * 32);
        float s = mb3[t];
        #pragma unroll
        for (int j = 0; j < 8; j++) {
            float4 wv4 = wr[j];
            s += wv4.x * t2[4 * j] + wv4.y * t2[4 * j + 1] + wv4.z * t2[4 * j + 2] + wv4.w * t2[4 * j + 3];
        }
        out[(size_t)b * 65 + t] = s;
    }
}

// ---------------------------------------------------------------------------
extern "C" void kernel_launch(void* const* d_in, const int* in_sizes, int n_in,
                              void* d_out, int out_size, void* d_ws, size_t ws_size,
                              hipStream_t stream)
{
    const float* x         = (const float*)d_in[0];
    const int*   cluster   = (const int*)  d_in[1];
    const float* expert_w  = (const float*)d_in[2];
    const float* cond_b    = (const float*)d_in[3];
    const float* route_emb = (const float*)d_in[4];
    const float* route_W   = (const float*)d_in[5];
    const float* route_b   = (const float*)d_in[6];
    const float* v1  = (const float*)d_in[7];
    const float* g1  = (const float*)d_in[8];
    const float* cb1 = (const float*)d_in[9];
    const float* a1  = (const float*)d_in[10];
    const float* v2  = (const float*)d_in[11];
    const float* g2  = (const float*)d_in[12];
    const float* cb2 = (const float*)d_in[13];
    const float* a2  = (const float*)d_in[14];
    const float* v3  = (const float*)d_in[15];
    const float* g3  = (const float*)d_in[16];
    const float* cb3 = (const float*)d_in[17];
    const float* a3  = (const float*)d_in[18];
    const float* emb2  = (const float*)d_in[19];
    const float* alpha = (const float*)d_in[20];
    const float* mW1 = (const float*)d_in[21];
    const float* mb1 = (const float*)d_in[22];
    const float* a4  = (const float*)d_in[23];
    const float* mW2 = (const float*)d_in[24];
    const float* mb2 = (const float*)d_in[25];
    const float* a5  = (const float*)d_in[26];
    const float* mW3 = (const float*)d_in[27];
    const float* mb3 = (const float*)d_in[28];
    float* ws  = (float*)d_ws;
    float* out = (float*)d_out;

    hipFuncSetAttribute((const void*)k_f1,  hipFuncAttributeMaxDynamicSharedMemorySize, 72448);
    hipFuncSetAttribute((const void*)k_f23, hipFuncAttributeMaxDynamicSharedMemorySize, 114112);

    k_prep<<<4152, 256, 0, stream>>>(x, v1, g1, v2, g2, v3, g3, ws);
    k_route<<<256, 256, 0, stream>>>(cluster, route_emb, route_W, route_b, expert_w, ws);
    k_f1<<<dim3(6, 256), 512, 72448, stream>>>(x, (const f16*)(ws + OFF_KERN), cond_b,
                                               (const f16*)(ws + OFF_W1), cb1, a1,
                                               (f16*)(ws + OFF_H1));
    k_f23<<<256, 1024, 114112, stream>>>((const f16*)(ws + OFF_H1), (const f16*)(ws + OFF_W2),
                                         cb2, a2, (const f16*)(ws + OFF_W3), cb3, a3,
                                         cluster, emb2, alpha,
                                         mW1, mb1, a4, mW2, mb2, a5, mW3, mb3, out);
}